// Round 1
// baseline (64.565 us; speedup 1.0000x reference)
//
#include <hip/hip_runtime.h>
#include <stdint.h>

#define V_CONST 50257
#define KTOP 50
#define CAND_CAP 1024
#define NTHREADS 1024
// JAX >= 0.4.36 defaults jax_threefry_partitionable=True. If next_token
// (output 0) mismatches while probs (output 1) passes, flip this to 0.
#define THREEFRY_PARTITIONABLE 1

__device__ __forceinline__ void tf_round(uint32_t &x0, uint32_t &x1, int r) {
  x0 += x1;
  x1 = (x1 << r) | (x1 >> (32 - r));
  x1 ^= x0;
}

// Threefry-2x32, 20 rounds, key = (0, 42)  [jax.random.key(42)]
__device__ __forceinline__ uint2 threefry_k_0_42(uint32_t x0, uint32_t x1) {
  const uint32_t ks0 = 0u;
  const uint32_t ks1 = 42u;
  const uint32_t ks2 = 0x1BD11BDAu ^ 0u ^ 42u;
  x0 += ks0; x1 += ks1;
  tf_round(x0, x1, 13); tf_round(x0, x1, 15); tf_round(x0, x1, 26); tf_round(x0, x1, 6);
  x0 += ks1; x1 += ks2 + 1u;
  tf_round(x0, x1, 17); tf_round(x0, x1, 29); tf_round(x0, x1, 16); tf_round(x0, x1, 24);
  x0 += ks2; x1 += ks0 + 2u;
  tf_round(x0, x1, 13); tf_round(x0, x1, 15); tf_round(x0, x1, 26); tf_round(x0, x1, 6);
  x0 += ks0; x1 += ks1 + 3u;
  tf_round(x0, x1, 17); tf_round(x0, x1, 29); tf_round(x0, x1, 16); tf_round(x0, x1, 24);
  x0 += ks1; x1 += ks2 + 4u;
  tf_round(x0, x1, 13); tf_round(x0, x1, 15); tf_round(x0, x1, 26); tf_round(x0, x1, 6);
  x0 += ks2; x1 += ks0 + 5u;
  uint2 r; r.x = x0; r.y = x1; return r;
}

// gumbel noise at flat position p of a (B,V) draw, matching
// jax.random.gumbel(key(42), (B,V), float32)
__device__ __forceinline__ float gumbel_at(uint32_t p, uint32_t half_total) {
  uint32_t bits;
#if THREEFRY_PARTITIONABLE
  // counts = iota(uint64); x0 = hi32 = 0, x1 = lo32 = p; bits = out0 ^ out1
  uint2 o = threefry_k_0_42(0u, p);
  bits = o.x ^ o.y;
#else
  // legacy: counts split in halves; bits = concat(out0, out1)
  if (p < half_total) {
    uint2 o = threefry_k_0_42(p, p + half_total);
    bits = o.x;
  } else {
    uint2 o = threefry_k_0_42(p - half_total, p);
    bits = o.y;
  }
#endif
  // uniform(minval=tiny, maxval=1): u = bitcast((bits>>9)|0x3F800000)-1;
  // (1-tiny) rounds to 1.0f so result = max(tiny, u + tiny)
  uint32_t ub = (bits >> 9) | 0x3F800000u;
  float u = __uint_as_float(ub) - 1.0f;
  u = u + 1.17549435e-38f;
  u = fmaxf(1.17549435e-38f, u);
  return -logf(-logf(u));
}

// monotonic float->uint mapping (larger float => larger uint)
__device__ __forceinline__ uint32_t f2u_desc(float f) {
  uint32_t b = __float_as_uint(f);
  return (b & 0x80000000u) ? ~b : (b | 0x80000000u);
}
__device__ __forceinline__ float u2f(uint32_t u) {
  uint32_t b = (u & 0x80000000u) ? (u & 0x7FFFFFFFu) : ~u;
  return __uint_as_float(b);
}

__global__ __launch_bounds__(NTHREADS, 1) void sample_kernel(
    const float* __restrict__ logits, const int* __restrict__ generated,
    float* __restrict__ out, int B, int T) {
  const int b = blockIdx.x;
  const int tid = threadIdx.x;
  const int V = V_CONST;

  __shared__ uint32_t mask[(V_CONST + 31) / 32];  // present-token bitmask
  __shared__ uint32_t hist[4096];                 // 12-bit radix histogram
  __shared__ uint32_t csum[256];
  __shared__ uint32_t cu[CAND_CAP];
  __shared__ int      cidx[CAND_CAP];
  __shared__ uint32_t su[CAND_CAP];
  __shared__ int      sidx[CAND_CAP];
  __shared__ float    eg[CAND_CAP];               // exp(x - max)
  __shared__ float    gg[CAND_CAP];               // gumbel noise
  __shared__ int      s_ncand, s_bsel, s_nsurv, s_rlast;
  __shared__ float    s_z2;

  for (int i = tid; i < (V_CONST + 31) / 32; i += NTHREADS) mask[i] = 0u;
  for (int i = tid; i < 4096; i += NTHREADS) hist[i] = 0u;
  if (tid == 0) s_ncand = 0;
  __syncthreads();

  // ---- present mask from generated row ----
  const int* grow = generated + (size_t)b * T;
  for (int i = tid; i < T; i += NTHREADS) {
    int tok = grow[i];
    atomicOr(&mask[tok >> 5], 1u << (tok & 31));
  }
  __syncthreads();

  const float* lrow = logits + (size_t)b * V;

  // ---- pass 1: histogram of top 12 bits of sortable(x) ----
  for (int v = tid; v < V; v += NTHREADS) {
    float x = lrow[v] / 0.8f;                       // / TEMPERATURE (IEEE div)
    if ((mask[v >> 5] >> (v & 31)) & 1u) x = x / 1.2f;  // / REP_PENALTY
    atomicAdd(&hist[f2u_desc(x) >> 20], 1u);
  }
  __syncthreads();

  // ---- select the bin containing the 50th largest ----
  if (tid < 256) {
    uint32_t s = 0;
    for (int j = 0; j < 16; j++) s += hist[tid * 16 + j];
    csum[tid] = s;
  }
  __syncthreads();
  if (tid == 0) {
    uint32_t acc = 0;
    int chunk = 255;
    for (; chunk > 0; chunk--) {
      if (acc + csum[chunk] >= (uint32_t)KTOP) break;
      acc += csum[chunk];
    }
    int bin = chunk * 16 + 15;
    for (; bin > chunk * 16; bin--) {
      if (acc + hist[bin] >= (uint32_t)KTOP) break;
      acc += hist[bin];
    }
    s_bsel = bin;
  }
  __syncthreads();
  const uint32_t ulo = (uint32_t)s_bsel << 20;

  // ---- pass 2: collect candidates (superset of top-50) ----
  for (int v = tid; v < V; v += NTHREADS) {
    float x = lrow[v] / 0.8f;
    if ((mask[v >> 5] >> (v & 31)) & 1u) x = x / 1.2f;
    uint32_t u = f2u_desc(x);
    if (u >= ulo) {
      int pos = atomicAdd(&s_ncand, 1);
      if (pos < CAND_CAP) { cu[pos] = u; cidx[pos] = v; }
    }
  }
  __syncthreads();

  int n = min(s_ncand, CAND_CAP);
  // ---- stable rank sort (descending by value, ties by smaller index) ----
  for (int i = tid; i < n; i += NTHREADS) {
    uint32_t ui = cu[i]; int ii = cidx[i];
    int rank = 0;
    for (int j = 0; j < n; j++) {
      uint32_t uj = cu[j];
      rank += (uj > ui) || (uj == ui && cidx[j] < ii);
    }
    su[rank] = ui; sidx[rank] = ii;
  }
  __syncthreads();

  // ---- top-k survivors: x >= kth (includes ties at kth) ----
  if (tid == 0) {
    int kpos = (n < KTOP) ? (n - 1) : (KTOP - 1);
    uint32_t kth = su[kpos];
    int ns = kpos + 1;
    while (ns < n && su[ns] == kth) ns++;
    s_nsurv = ns;
  }
  __syncthreads();
  const int nsurv = s_nsurv;
  const float s0 = u2f(su[0]);
  const uint32_t half_total = (uint32_t)((size_t)B * V / 2);

  // ---- parallel: exp(x - max) and gumbel at kept indices ----
  for (int r = tid; r < nsurv; r += NTHREADS) {
    float f = u2f(su[r]);
    eg[r] = expf(f - s0);
    gg[r] = gumbel_at((uint32_t)(b * V + sidx[r]), half_total);
  }
  __syncthreads();

  // ---- serial: top-p cutoff, final Z, categorical sample ----
  if (tid == 0) {
    float zall = 0.f;
    for (int r = 0; r < nsurv; r++) zall += eg[r];
    float cum = 0.f;
    int rlast = 0;
    for (int r = 0; r < nsurv; r++) {
      cum += eg[r] / zall;
      if (r == 0 || cum <= 0.9f) rlast = r;   // keep prefix; rank0 forced keep
      else break;                              // cum monotonic increasing
    }
    float z2 = 0.f;
    for (int r = 0; r <= rlast; r++) z2 += eg[r];
    // argmax(x + g) over kept set; ties -> smallest token index
    float best = -3.402823466e38f; int besti = V;
    for (int r = 0; r <= rlast; r++) {
      float sc = u2f(su[r]) + gg[r];
      int idx = sidx[r];
      if (sc > best || (sc == best && idx < besti)) { best = sc; besti = idx; }
    }
    out[b] = (float)besti;       // next_token, as float (d_out is float32)
    s_rlast = rlast; s_z2 = z2;
  }
  __syncthreads();
  const int rlast = s_rlast;
  const float z2 = s_z2;

  // ---- zero-fill probs row (vectorized), then scatter kept probs ----
  {
    size_t e0 = (size_t)B + (size_t)b * V;   // probs start after B tokens
    size_t e1 = e0 + V;
    size_t a0 = (e0 + 3) & ~(size_t)3;
    size_t a1 = e1 & ~(size_t)3;
    for (size_t e = e0 + tid; e < a0; e += NTHREADS) out[e] = 0.f;
    float4* o4 = (float4*)(out + a0);
    size_t n4 = (a1 - a0) >> 2;
    float4 z4 = make_float4(0.f, 0.f, 0.f, 0.f);
    for (size_t i = tid; i < n4; i += NTHREADS) o4[i] = z4;
    for (size_t e = a1 + tid; e < e1; e += NTHREADS) out[e] = 0.f;
  }
  __syncthreads();
  {
    float* prow = out + B + (size_t)b * V;
    for (int r = tid; r <= rlast; r += NTHREADS) {
      prow[sidx[r]] = eg[r] / z2;
    }
  }
}

extern "C" void kernel_launch(void* const* d_in, const int* in_sizes, int n_in,
                              void* d_out, int out_size, void* d_ws, size_t ws_size,
                              hipStream_t stream) {
  const float* logits = (const float*)d_in[0];
  const int* generated = (const int*)d_in[1];
  float* out = (float*)d_out;
  const int B = in_sizes[0] / V_CONST;
  const int T = in_sizes[1] / B;
  hipLaunchKernelGGL(sample_kernel, dim3(B), dim3(NTHREADS), 0, stream,
                     logits, generated, out, B, T);
}

// Round 2
// 62.037 us; speedup vs baseline: 1.0408x; 1.0408x over previous
//
#include <hip/hip_runtime.h>
#include <stdint.h>

#define V_CONST 50257
#define NMASK ((V_CONST + 31) / 32)
#define KTOP 50
#define CAND_CAP 2048
#define NTHREADS 1024
#define NITER 13  // 13*4*1024 = 53248 >= 50257
// JAX >= 0.4.36 defaults jax_threefry_partitionable=True (verified: passed R1).
#define THREEFRY_PARTITIONABLE 1

__device__ __forceinline__ void tf_round(uint32_t &x0, uint32_t &x1, int r) {
  x0 += x1;
  x1 = (x1 << r) | (x1 >> (32 - r));
  x1 ^= x0;
}

// Threefry-2x32, 20 rounds, key = (0, 42)  [jax.random.key(42)]
__device__ __forceinline__ uint2 threefry_k_0_42(uint32_t x0, uint32_t x1) {
  const uint32_t ks0 = 0u;
  const uint32_t ks1 = 42u;
  const uint32_t ks2 = 0x1BD11BDAu ^ 0u ^ 42u;
  x0 += ks0; x1 += ks1;
  tf_round(x0, x1, 13); tf_round(x0, x1, 15); tf_round(x0, x1, 26); tf_round(x0, x1, 6);
  x0 += ks1; x1 += ks2 + 1u;
  tf_round(x0, x1, 17); tf_round(x0, x1, 29); tf_round(x0, x1, 16); tf_round(x0, x1, 24);
  x0 += ks2; x1 += ks0 + 2u;
  tf_round(x0, x1, 13); tf_round(x0, x1, 15); tf_round(x0, x1, 26); tf_round(x0, x1, 6);
  x0 += ks0; x1 += ks1 + 3u;
  tf_round(x0, x1, 17); tf_round(x0, x1, 29); tf_round(x0, x1, 16); tf_round(x0, x1, 24);
  x0 += ks1; x1 += ks2 + 4u;
  tf_round(x0, x1, 13); tf_round(x0, x1, 15); tf_round(x0, x1, 26); tf_round(x0, x1, 6);
  x0 += ks2; x1 += ks0 + 5u;
  uint2 r; r.x = x0; r.y = x1; return r;
}

__device__ __forceinline__ float gumbel_at(uint32_t p, uint32_t half_total) {
  uint32_t bits;
#if THREEFRY_PARTITIONABLE
  uint2 o = threefry_k_0_42(0u, p);
  bits = o.x ^ o.y;
#else
  if (p < half_total) {
    uint2 o = threefry_k_0_42(p, p + half_total);
    bits = o.x;
  } else {
    uint2 o = threefry_k_0_42(p - half_total, p);
    bits = o.y;
  }
#endif
  uint32_t ub = (bits >> 9) | 0x3F800000u;
  float u = __uint_as_float(ub) - 1.0f;
  u = u + 1.17549435e-38f;
  u = fmaxf(1.17549435e-38f, u);
  return -logf(-logf(u));
}

// monotonic float->uint mapping (larger float => larger uint)
__device__ __forceinline__ uint32_t f2u_desc(float f) {
  uint32_t b = __float_as_uint(f);
  return (b & 0x80000000u) ? ~b : (b | 0x80000000u);
}
__device__ __forceinline__ float u2f(uint32_t u) {
  uint32_t b = (u & 0x80000000u) ? (u & 0x7FFFFFFFu) : ~u;
  return __uint_as_float(b);
}

__device__ __forceinline__ uint32_t penal(float xr, int v, const uint32_t* msk) {
  float x = xr / 0.8f;                                  // / TEMPERATURE (IEEE)
  if ((msk[v >> 5] >> (v & 31)) & 1u) x = x / 1.2f;     // / REP_PENALTY (IEEE)
  return f2u_desc(x);
}

__global__ __launch_bounds__(NTHREADS, 1) void sample_kernel(
    const float* __restrict__ logits, const int* __restrict__ generated,
    float* __restrict__ out, int B, int T) {
  const int b = blockIdx.x;
  const int tid = threadIdx.x;
  const int lane = tid & 63;
  const int wid = tid >> 6;

  __shared__ uint32_t mask[NMASK];
  __shared__ uint32_t cu[CAND_CAP];
  __shared__ int      cidx[CAND_CAP];
  __shared__ uint32_t su[CAND_CAP];
  __shared__ int      sidx[CAND_CAP];
  __shared__ float    eg[CAND_CAP];
  __shared__ float    gg[CAND_CAP];
  __shared__ uint32_t wred[16];
  __shared__ int s_ncand, s_nsurv, s_rlast;
  __shared__ float s_z2;

  for (int i = tid; i < NMASK; i += NTHREADS) mask[i] = 0u;
  if (tid == 0) s_ncand = 0;
  __syncthreads();

  // ---- present mask ----
  const int* grow = generated + (size_t)b * T;
  for (int i = tid; i < T; i += NTHREADS) {
    int tok = grow[i];
    atomicOr(&mask[tok >> 5], 1u << (tok & 31));
  }
  __syncthreads();

  // ---- single pass: float4 loads -> penalized sortable uints in registers ----
  const int aoff = (4 - (b & 3)) & 3;           // b*V mod 4 == b mod 4
  const int tailn = (V_CONST - aoff) & 3;
  const int body4 = (V_CONST - aoff) >> 2;      // 12563 or 12564 (> 12*1024)
  const int nextra = aoff + tailn;              // <= 5
  const float* lrow = logits + (size_t)b * V_CONST;
  const float4* arow4 = (const float4*)(lrow + aoff);

  uint32_t uu[NITER][4];
  #pragma unroll
  for (int i = 0; i < NITER; i++) {
    int idx4 = i * NTHREADS + tid;
    if (i < NITER - 1 || idx4 < body4) {        // iters 0..11 always in body
      float4 r = arow4[idx4];
      int v0 = aoff + idx4 * 4;
      uu[i][0] = penal(r.x, v0 + 0, mask);
      uu[i][1] = penal(r.y, v0 + 1, mask);
      uu[i][2] = penal(r.z, v0 + 2, mask);
      uu[i][3] = penal(r.w, v0 + 3, mask);
    } else {
      uu[i][0] = 0u; uu[i][1] = 0u; uu[i][2] = 0u; uu[i][3] = 0u;
    }
  }
  // head/tail extras (<=5 elements) live in sentinel slot [NITER-1][3] of the
  // top threads (their idx4 >= 13307 > body4, so that slot is free)
  {
    int e = (NTHREADS - 1) - tid;
    if (e < nextra) {
      int v = (e < aoff) ? e : (V_CONST - tailn) + (e - aoff);
      uu[NITER - 1][3] = penal(lrow[v], v, mask);
    }
  }

  // ---- zero-fill probs row now; store-acks drain under later phases ----
  {
    size_t e0 = (size_t)B + (size_t)b * V_CONST;
    size_t e1 = e0 + V_CONST;
    size_t a0 = (e0 + 3) & ~(size_t)3;
    size_t a1 = e1 & ~(size_t)3;
    for (size_t e = e0 + tid; e < a0; e += NTHREADS) out[e] = 0.f;
    float4* o4 = (float4*)(out + a0);
    size_t n4 = (a1 - a0) >> 2;
    float4 z4 = make_float4(0.f, 0.f, 0.f, 0.f);
    for (size_t i = tid; i < n4; i += NTHREADS) o4[i] = z4;
    for (size_t e = a1 + tid; e < e1; e += NTHREADS) out[e] = 0.f;
  }

  // ---- block max of u ----
  uint32_t mx = 0u;
  #pragma unroll
  for (int i = 0; i < NITER; i++)
    #pragma unroll
    for (int j = 0; j < 4; j++) mx = max(mx, uu[i][j]);
  for (int off = 32; off > 0; off >>= 1) mx = max(mx, (uint32_t)__shfl_down(mx, off, 64));
  __syncthreads();
  if (lane == 0) wred[wid] = mx;
  __syncthreads();
  uint32_t M = 0u;
  for (int w = 0; w < 16; w++) M = max(M, wred[w]);

  // ---- binary search a cutoff c with KTOP <= count(u>=c) <= CAND_CAP ----
  // sentinels are u==0 and c>=1, so they never count
  uint32_t lo = 0u, hi = M + 1u;
  uint32_t c = (M > (1u << 22)) ? (M - (1u << 22)) : 1u;
  int count = 0;
  for (int iter = 0; iter < 64; iter++) {
    int cnt = 0;
    #pragma unroll
    for (int i = 0; i < NITER; i++)
      #pragma unroll
      for (int j = 0; j < 4; j++) cnt += (uu[i][j] >= c) ? 1 : 0;
    for (int off = 32; off > 0; off >>= 1) cnt += __shfl_down(cnt, off, 64);
    __syncthreads();
    if (lane == 0) wred[wid] = (uint32_t)cnt;
    __syncthreads();
    count = 0;
    for (int w = 0; w < 16; w++) count += (int)wred[w];
    if (count >= KTOP && count <= CAND_CAP) break;
    if (count < KTOP) {
      hi = c;
      c = (lo > 0u) ? lo + (hi - lo) / 2u
                    : ((c > (1u << 22)) ? c - (1u << 22) : 1u);
    } else {
      lo = c;
      c = lo + (hi - lo) / 2u;
    }
    if (c <= lo || c >= hi) break;  // degenerate (massive exact ties) — unreachable for real data
  }

  // ---- collect candidates (exactly `count` of them) ----
  #pragma unroll
  for (int i = 0; i < NITER; i++) {
    #pragma unroll
    for (int j = 0; j < 4; j++) {
      uint32_t u = uu[i][j];
      if (u >= c) {
        int v;
        int e = (NTHREADS - 1) - tid;
        if (i == NITER - 1 && j == 3 && e < nextra) {
          v = (e < aoff) ? e : (V_CONST - tailn) + (e - aoff);
        } else {
          v = aoff + (i * NTHREADS + tid) * 4 + j;
        }
        int pos = atomicAdd(&s_ncand, 1);
        if (pos < CAND_CAP) { cu[pos] = u; cidx[pos] = v; }
      }
    }
  }
  __syncthreads();

  const int n = min(s_ncand, CAND_CAP);
  // ---- stable rank sort (descending, ties by smaller index) ----
  for (int i2 = tid; i2 < n; i2 += NTHREADS) {
    uint32_t ui = cu[i2]; int ii = cidx[i2];
    int rank = 0;
    for (int j = 0; j < n; j++) {
      uint32_t uj = cu[j];
      rank += ((uj > ui) || (uj == ui && cidx[j] < ii)) ? 1 : 0;
    }
    su[rank] = ui; sidx[rank] = ii;
  }
  __syncthreads();

  // ---- top-k survivors: x >= kth (includes ties) ----
  if (tid == 0) {
    int kpos = (n < KTOP) ? (n - 1) : (KTOP - 1);
    uint32_t kth = su[kpos];
    int ns = kpos + 1;
    while (ns < n && su[ns] == kth) ns++;
    s_nsurv = ns;
  }
  __syncthreads();
  const int nsurv = s_nsurv;
  const float s0 = u2f(su[0]);
  const uint32_t half_total = (uint32_t)((size_t)256 * V_CONST / 2);

  for (int r = tid; r < nsurv; r += NTHREADS) {
    float f = u2f(su[r]);
    eg[r] = expf(f - s0);
    gg[r] = gumbel_at((uint32_t)(b * V_CONST + sidx[r]), half_total);
  }
  __syncthreads();

  // ---- serial: top-p cutoff, Z, categorical sample ----
  if (tid == 0) {
    float zall = 0.f;
    for (int r = 0; r < nsurv; r++) zall += eg[r];
    float cum = 0.f;
    int rlast = 0;
    for (int r = 0; r < nsurv; r++) {
      cum += eg[r] / zall;
      if (r == 0 || cum <= 0.9f) rlast = r;
      else break;
    }
    float z2 = 0.f;
    for (int r = 0; r <= rlast; r++) z2 += eg[r];
    float best = -3.402823466e38f; int besti = V_CONST;
    for (int r = 0; r <= rlast; r++) {
      float sc = u2f(su[r]) + gg[r];
      int idx = sidx[r];
      if (sc > best || (sc == best && idx < besti)) { best = sc; besti = idx; }
    }
    out[b] = (float)besti;
    s_rlast = rlast; s_z2 = z2;
  }
  __syncthreads();
  const int rlast = s_rlast;
  const float z2 = s_z2;

  // ---- scatter kept probs (row already zero-filled; barriers ordered it) ----
  {
    float* prow = out + B + (size_t)b * V_CONST;
    for (int r = tid; r <= rlast; r += NTHREADS) {
      prow[sidx[r]] = eg[r] / z2;
    }
  }
}

extern "C" void kernel_launch(void* const* d_in, const int* in_sizes, int n_in,
                              void* d_out, int out_size, void* d_ws, size_t ws_size,
                              hipStream_t stream) {
  const float* logits = (const float*)d_in[0];
  const int* generated = (const int*)d_in[1];
  float* out = (float*)d_out;
  const int B = in_sizes[0] / V_CONST;
  const int T = in_sizes[1] / B;
  hipLaunchKernelGGL(sample_kernel, dim3(B), dim3(NTHREADS), 0, stream,
                     logits, generated, out, B, T);
}

// Round 3
// 33.978 us; speedup vs baseline: 1.9002x; 1.8258x over previous
//
#include <hip/hip_runtime.h>
#include <stdint.h>

#define V_CONST 50257
#define NMASK ((V_CONST + 31) / 32)
#define KTOP 50
#define CAND_CAP 1024
#define NTHREADS 1024
#define C_TEMP 1.25f
#define C_PEN ((float)(1.25 / 1.2))
// JAX >= 0.4.36 threefry_partitionable path — verified (R1/R2 passed).
#define THREEFRY_PARTITIONABLE 1

__device__ __forceinline__ void tf_round(uint32_t &x0, uint32_t &x1, int r) {
  x0 += x1;
  x1 = (x1 << r) | (x1 >> (32 - r));
  x1 ^= x0;
}

// Threefry-2x32, 20 rounds, key = (0, 42)  [jax.random.key(42)]
__device__ __forceinline__ uint2 threefry_k_0_42(uint32_t x0, uint32_t x1) {
  const uint32_t ks0 = 0u;
  const uint32_t ks1 = 42u;
  const uint32_t ks2 = 0x1BD11BDAu ^ 0u ^ 42u;
  x0 += ks0; x1 += ks1;
  tf_round(x0, x1, 13); tf_round(x0, x1, 15); tf_round(x0, x1, 26); tf_round(x0, x1, 6);
  x0 += ks1; x1 += ks2 + 1u;
  tf_round(x0, x1, 17); tf_round(x0, x1, 29); tf_round(x0, x1, 16); tf_round(x0, x1, 24);
  x0 += ks2; x1 += ks0 + 2u;
  tf_round(x0, x1, 13); tf_round(x0, x1, 15); tf_round(x0, x1, 26); tf_round(x0, x1, 6);
  x0 += ks0; x1 += ks1 + 3u;
  tf_round(x0, x1, 17); tf_round(x0, x1, 29); tf_round(x0, x1, 16); tf_round(x0, x1, 24);
  x0 += ks1; x1 += ks2 + 4u;
  tf_round(x0, x1, 13); tf_round(x0, x1, 15); tf_round(x0, x1, 26); tf_round(x0, x1, 6);
  x0 += ks2; x1 += ks0 + 5u;
  uint2 r; r.x = x0; r.y = x1; return r;
}

__device__ __forceinline__ float gumbel_at(uint32_t p, uint32_t half_total) {
  uint32_t bits;
#if THREEFRY_PARTITIONABLE
  uint2 o = threefry_k_0_42(0u, p);
  bits = o.x ^ o.y;
#else
  if (p < half_total) {
    uint2 o = threefry_k_0_42(p, p + half_total);
    bits = o.x;
  } else {
    uint2 o = threefry_k_0_42(p - half_total, p);
    bits = o.y;
  }
#endif
  uint32_t ub = (bits >> 9) | 0x3F800000u;
  float u = __uint_as_float(ub) - 1.0f;
  u = u + 1.17549435e-38f;
  u = fmaxf(1.17549435e-38f, u);
  return -logf(-logf(u));
}

// monotonic float->uint mapping (larger float => larger uint)
__device__ __forceinline__ uint32_t f2u_desc(float f) {
  uint32_t b = __float_as_uint(f);
  return (b & 0x80000000u) ? ~b : (b | 0x80000000u);
}
__device__ __forceinline__ float u2f(uint32_t u) {
  uint32_t b = (u & 0x80000000u) ? (u & 0x7FFFFFFFu) : ~u;
  return __uint_as_float(b);
}

__global__ __launch_bounds__(NTHREADS) void sample_kernel(
    const float* __restrict__ logits, const int* __restrict__ generated,
    float* __restrict__ out, int B, int T) {
  const int b = blockIdx.x;
  const int tid = threadIdx.x;

  __shared__ uint32_t mask[NMASK];
  __shared__ uint32_t candA[CAND_CAP];  // raw float bits, then exact key (in place)
  __shared__ int      cidx[CAND_CAP];
  __shared__ uint32_t su[CAND_CAP];
  __shared__ int      sidx[CAND_CAP];
  __shared__ float    eg[CAND_CAP];
  __shared__ float    gg[CAND_CAP];
  __shared__ int s_ncand, s_nsurv, s_rlast;
  __shared__ float s_z2;

  // ---- zero-fill probs row FIRST: stores drain under all later phases ----
  {
    size_t e0 = (size_t)B + (size_t)b * V_CONST;
    size_t e1 = e0 + V_CONST;
    size_t a0 = (e0 + 3) & ~(size_t)3;
    size_t a1 = e1 & ~(size_t)3;
    for (size_t e = e0 + tid; e < a0; e += NTHREADS) out[e] = 0.f;
    float4* o4 = (float4*)(out + a0);
    size_t n4 = (a1 - a0) >> 2;
    float4 z4 = make_float4(0.f, 0.f, 0.f, 0.f);
    for (size_t i = tid; i < n4; i += NTHREADS) o4[i] = z4;
    for (size_t e = a1 + tid; e < e1; e += NTHREADS) out[e] = 0.f;
  }

  // ---- present-token bitmask ----
  for (int i = tid; i < NMASK; i += NTHREADS) mask[i] = 0u;
  __syncthreads();
  const int* grow = generated + (size_t)b * T;
  for (int i = tid; i < T; i += NTHREADS) {
    int tok = grow[i];
    atomicOr(&mask[tok >> 5], 1u << (tok & 31));
  }
  __syncthreads();

  const float* lrow = logits + (size_t)b * V_CONST;
  const int aoff = (4 - (b & 3)) & 3;       // (b*V) mod 4 == b mod 4
  const int tailn = (V_CONST - aoff) & 3;
  const int body4 = (V_CONST - aoff) >> 2;
  const float4* arow4 = (const float4*)(lrow + aoff);

  // ---- collect loop: cheap monotone screen, exact verify ----
  float thr = 13.0f;                 // ~3 sigma of x/0.8 for this distribution
  uint32_t ulo = 0u, uhi = 0xFFFFFFFFu;   // bisection bounds (fallback only)
  int n = 0;

  for (int attempt = 0; attempt < 64; ++attempt) {
    __syncthreads();
    if (tid == 0) s_ncand = 0;
    __syncthreads();

    // screen pass: approx key = x * (present ? C_PEN : C_TEMP), monotone in x
    for (int q = tid; q < body4; q += NTHREADS) {
      float4 r = arow4[q];
      int v0 = aoff + (q << 2);
      uint32_t w = (mask[v0 >> 5] >> (v0 & 31)) & 0xFu;
      float m0 = (w & 1u) ? C_PEN : C_TEMP;
      float m1 = (w & 2u) ? C_PEN : C_TEMP;
      float m2 = (w & 4u) ? C_PEN : C_TEMP;
      float m3 = (w & 8u) ? C_PEN : C_TEMP;
      if (r.x * m0 >= thr) { int p = atomicAdd(&s_ncand, 1); if (p < CAND_CAP) { candA[p] = __float_as_uint(r.x); cidx[p] = v0; } }
      if (r.y * m1 >= thr) { int p = atomicAdd(&s_ncand, 1); if (p < CAND_CAP) { candA[p] = __float_as_uint(r.y); cidx[p] = v0 + 1; } }
      if (r.z * m2 >= thr) { int p = atomicAdd(&s_ncand, 1); if (p < CAND_CAP) { candA[p] = __float_as_uint(r.z); cidx[p] = v0 + 2; } }
      if (r.w * m3 >= thr) { int p = atomicAdd(&s_ncand, 1); if (p < CAND_CAP) { candA[p] = __float_as_uint(r.w); cidx[p] = v0 + 3; } }
    }
    // head/tail extras (<= 5 elems, threads 0..4)
    if (tid < aoff + tailn) {
      int v = (tid < aoff) ? tid : (V_CONST - tailn) + (tid - aoff);
      float x = lrow[v];
      float m = ((mask[v >> 5] >> (v & 31)) & 1u) ? C_PEN : C_TEMP;
      if (x * m >= thr) { int p = atomicAdd(&s_ncand, 1); if (p < CAND_CAP) { candA[p] = __float_as_uint(x); cidx[p] = v; } }
    }
    __syncthreads();

    const int total = s_ncand;
    n = (total < CAND_CAP) ? total : CAND_CAP;
    const bool window = (total >= KTOP && total <= CAND_CAP);
    const bool last = (attempt == 63);

    if (window || last) {
      if (n > 0) {
        // exact keys (true IEEE divisions), in place
        for (int i = tid; i < n; i += NTHREADS) {
          float x = __uint_as_float(candA[i]);
          int v = cidx[i];
          float xe = x / 0.8f;
          if ((mask[v >> 5] >> (v & 31)) & 1u) xe = xe / 1.2f;
          candA[i] = f2u_desc(xe);
        }
        __syncthreads();
        // stable rank sort (descending, ties by smaller index)
        for (int i = tid; i < n; i += NTHREADS) {
          uint32_t ui = candA[i]; int ii = cidx[i];
          int rank = 0;
          for (int j = 0; j < n; j++) {
            uint32_t uj = candA[j];
            rank += ((uj > ui) || (uj == ui && cidx[j] < ii)) ? 1 : 0;
          }
          su[rank] = ui; sidx[rank] = ii;
        }
        __syncthreads();
      }
      if (window) {
        // certificate: non-candidates have exact key < f2u(thr)+2 ulp;
        // if candidate 50th exact key clears that by margin, superset proven.
        uint32_t ut = f2u_desc(thr);
        if (su[KTOP - 1] >= ut + 64u) break;
        if (last) break;
        thr = u2f(su[KTOP - 1] >= 96u ? su[KTOP - 1] - 96u : 0u);  // re-scan just below 50th
      } else {
        break;  // last attempt: proceed best-effort
      }
    } else if (total < KTOP) {
      uhi = f2u_desc(thr);
      if (attempt == 0) thr = 11.0f;          // tuned one-step widen (~2.2 sigma)
      else {
        uint32_t mid = ulo + (uhi - ulo) / 2u;
        if (mid >= uhi) mid = uhi - 1u;
        thr = u2f(mid);
      }
    } else {  // total > CAND_CAP
      ulo = f2u_desc(thr);
      uint32_t mid = ulo + (uhi - ulo) / 2u;
      if (mid <= ulo) mid = ulo + 1u;
      thr = u2f(mid);
    }
  }

  if (n == 0) {  // unreachable for real data; avoid garbage
    if (tid == 0) out[b] = 0.f;
    return;
  }

  // ---- top-k survivors: x >= kth (includes ties) ----
  if (tid == 0) {
    int kpos = (n < KTOP) ? (n - 1) : (KTOP - 1);
    uint32_t kth = su[kpos];
    int ns = kpos + 1;
    while (ns < n && su[ns] == kth) ns++;
    s_nsurv = ns;
  }
  __syncthreads();
  const int nsurv = s_nsurv;
  const float s0 = u2f(su[0]);
  const uint32_t half_total = (uint32_t)((size_t)256 * V_CONST / 2);

  for (int r = tid; r < nsurv; r += NTHREADS) {
    float f = u2f(su[r]);
    eg[r] = expf(f - s0);
    gg[r] = gumbel_at((uint32_t)(b * V_CONST + sidx[r]), half_total);
  }
  __syncthreads();

  // ---- serial: top-p cutoff, Z, categorical sample ----
  if (tid == 0) {
    float zall = 0.f;
    for (int r = 0; r < nsurv; r++) zall += eg[r];
    float cum = 0.f;
    int rlast = 0;
    for (int r = 0; r < nsurv; r++) {
      cum += eg[r] / zall;
      if (r == 0 || cum <= 0.9f) rlast = r;
      else break;
    }
    float z2 = 0.f;
    for (int r = 0; r <= rlast; r++) z2 += eg[r];
    float best = -3.402823466e38f; int besti = V_CONST;
    for (int r = 0; r <= rlast; r++) {
      float sc = u2f(su[r]) + gg[r];
      int idx = sidx[r];
      if (sc > best || (sc == best && idx < besti)) { best = sc; besti = idx; }
    }
    out[b] = (float)besti;
    s_rlast = rlast; s_z2 = z2;
  }
  __syncthreads();
  const int rlast = s_rlast;
  const float z2 = s_z2;

  // ---- scatter kept probs (row zero-filled at top; barriers ordered it) ----
  {
    float* prow = out + B + (size_t)b * V_CONST;
    for (int r = tid; r <= rlast; r += NTHREADS) {
      prow[sidx[r]] = eg[r] / z2;
    }
  }
}

extern "C" void kernel_launch(void* const* d_in, const int* in_sizes, int n_in,
                              void* d_out, int out_size, void* d_ws, size_t ws_size,
                              hipStream_t stream) {
  const float* logits = (const float*)d_in[0];
  const int* generated = (const int*)d_in[1];
  float* out = (float*)d_out;
  const int B = in_sizes[0] / V_CONST;
  const int T = in_sizes[1] / B;
  hipLaunchKernelGGL(sample_kernel, dim3(B), dim3(NTHREADS), 0, stream,
                     logits, generated, out, B, T);
}